// Round 1
// baseline (3405.246 us; speedup 1.0000x reference)
//
#include <hip/hip_runtime.h>

// ---------------------------------------------------------------------------
// GCN 3-layer + edge weights, fp32 baseline.
// Pipeline: res = x@Wr+br ; 3x { zero agg; scatter(x_l)->agg; gemm(agg)->h } ;
//           out = h@Wop+bop
// ---------------------------------------------------------------------------

#define NF 128  // feature width for all hidden layers

// --- edge scatter: agg[dst] += x[src] * ew, 32 threads (float4 each) per edge
__global__ __launch_bounds__(256) void scatter_edges(
    const float* __restrict__ x, const int* __restrict__ src,
    const int* __restrict__ dst, const float* __restrict__ ew,
    float* __restrict__ agg, int n_edges)
{
    int gid = blockIdx.x * 256 + threadIdx.x;
    int e = gid >> 5;
    if (e >= n_edges) return;
    int f = (gid & 31) << 2;          // float offset 0..124, 16B aligned
    int s = src[e];
    int d = dst[e];
    float w = ew[e];
    const float4 v = *reinterpret_cast<const float4*>(x + (size_t)s * NF + f);
    float* o = agg + (size_t)d * NF + f;
    atomicAdd(o + 0, v.x * w);
    atomicAdd(o + 1, v.y * w);
    atomicAdd(o + 2, v.z * w);
    atomicAdd(o + 3, v.w * w);
}

// --- [nrows,128] @ [128,128] + bias (+res) (+relu), fp32
// block: 256 thr, tile 64 rows x 128 cols, thread tile 4x8, BK=32
template<int RELU, int RES>
__global__ __launch_bounds__(256) void gemm_nk128(
    const float* __restrict__ A, const float* __restrict__ W,
    const float* __restrict__ bias, const float* __restrict__ resid,
    float* __restrict__ out, int nrows)
{
    __shared__ float As[32][64];    // [k][r] transposed
    __shared__ float Bs[32][128];   // [k][c]
    const int tid = threadIdx.x;
    const int row0 = blockIdx.x * 64;
    const int tc = tid & 15;        // cols tc*8 .. tc*8+7
    const int tr = tid >> 4;        // rows tr*4 .. tr*4+3

    float acc[4][8];
    #pragma unroll
    for (int i = 0; i < 4; i++)
        #pragma unroll
        for (int j = 0; j < 8; j++) acc[i][j] = 0.f;

    for (int k0 = 0; k0 < 128; k0 += 32) {
        // stage A transposed: 64 rows x 32 k = 512 float4
        #pragma unroll
        for (int i = 0; i < 2; i++) {
            int t = tid + i * 256;          // 0..511
            int r = t & 63;
            int kk = (t >> 6) << 2;         // 0,4,...,28
            int gr = row0 + r;
            float4 v = make_float4(0.f, 0.f, 0.f, 0.f);
            if (gr < nrows)
                v = *reinterpret_cast<const float4*>(A + (size_t)gr * NF + k0 + kk);
            As[kk + 0][r] = v.x;
            As[kk + 1][r] = v.y;
            As[kk + 2][r] = v.z;
            As[kk + 3][r] = v.w;
        }
        // stage B: 32 x 128 = 1024 float4-quarters
        #pragma unroll
        for (int i = 0; i < 4; i++) {
            int t = tid + i * 256;          // 0..1023
            int kk = t >> 5;                // 0..31
            int c = (t & 31) << 2;
            *reinterpret_cast<float4*>(&Bs[kk][c]) =
                *reinterpret_cast<const float4*>(W + (size_t)(k0 + kk) * NF + c);
        }
        __syncthreads();
        #pragma unroll
        for (int k = 0; k < 32; k++) {
            float4 a  = *reinterpret_cast<float4*>(&As[k][tr << 2]);
            float4 b0 = *reinterpret_cast<float4*>(&Bs[k][tc << 3]);
            float4 b1 = *reinterpret_cast<float4*>(&Bs[k][(tc << 3) + 4]);
            float av[4] = {a.x, a.y, a.z, a.w};
            float bv[8] = {b0.x, b0.y, b0.z, b0.w, b1.x, b1.y, b1.z, b1.w};
            #pragma unroll
            for (int i = 0; i < 4; i++)
                #pragma unroll
                for (int j = 0; j < 8; j++)
                    acc[i][j] = fmaf(av[i], bv[j], acc[i][j]);
        }
        __syncthreads();
    }

    #pragma unroll
    for (int i = 0; i < 4; i++) {
        int gr = row0 + (tr << 2) + i;
        if (gr < nrows) {
            #pragma unroll
            for (int j = 0; j < 8; j++) {
                int c = (tc << 3) + j;
                float v = acc[i][j] + bias[c];
                if (RES) v += resid[(size_t)gr * NF + c];
                if (RELU) v = fmaxf(v, 0.f);
                out[(size_t)gr * NF + c] = v;
            }
        }
    }
}

// --- [nrows,128] @ [128,40] + bias
// block: 256 thr, tile 128 rows x 40 cols, thread tile 2x10, BK=32
__global__ __launch_bounds__(256) void gemm_out40(
    const float* __restrict__ H, const float* __restrict__ Wop,
    const float* __restrict__ bop, float* __restrict__ out, int nrows)
{
    __shared__ float Hs[32][128];      // [k][r]
    __shared__ float Ws[128 * 40];     // full Wop row-major
    const int tid = threadIdx.x;
    const int row0 = blockIdx.x * 128;
    const int tc = tid & 3;            // cols tc*10 .. tc*10+9
    const int tr = tid >> 2;           // rows tr*2, tr*2+1

    #pragma unroll
    for (int i = 0; i < 20; i++) Ws[tid + i * 256] = Wop[tid + i * 256];

    float acc[2][10];
    #pragma unroll
    for (int i = 0; i < 2; i++)
        #pragma unroll
        for (int j = 0; j < 10; j++) acc[i][j] = 0.f;

    for (int k0 = 0; k0 < 128; k0 += 32) {
        #pragma unroll
        for (int i = 0; i < 4; i++) {
            int t = tid + i * 256;      // 0..1023
            int r = t & 127;
            int kk = (t >> 7) << 2;     // 0,4,...,28
            int gr = row0 + r;
            float4 v = make_float4(0.f, 0.f, 0.f, 0.f);
            if (gr < nrows)
                v = *reinterpret_cast<const float4*>(H + (size_t)gr * NF + k0 + kk);
            Hs[kk + 0][r] = v.x;
            Hs[kk + 1][r] = v.y;
            Hs[kk + 2][r] = v.z;
            Hs[kk + 3][r] = v.w;
        }
        __syncthreads();
        #pragma unroll
        for (int k = 0; k < 32; k++) {
            float2 a = *reinterpret_cast<float2*>(&Hs[k][tr * 2]);
            #pragma unroll
            for (int j = 0; j < 10; j++) {
                float b = Ws[(k0 + k) * 40 + tc * 10 + j];
                acc[0][j] = fmaf(a.x, b, acc[0][j]);
                acc[1][j] = fmaf(a.y, b, acc[1][j]);
            }
        }
        __syncthreads();
    }

    #pragma unroll
    for (int i = 0; i < 2; i++) {
        int gr = row0 + tr * 2 + i;
        if (gr < nrows) {
            #pragma unroll
            for (int j = 0; j < 10; j++) {
                int c = tc * 10 + j;
                out[(size_t)gr * 40 + c] = acc[i][j] + bop[c];
            }
        }
    }
}

extern "C" void kernel_launch(void* const* d_in, const int* in_sizes, int n_in,
                              void* d_out, int out_size, void* d_ws, size_t ws_size,
                              hipStream_t stream)
{
    const float* x   = (const float*)d_in[0];
    const int*   src = (const int*)d_in[1];
    const int*   dst = (const int*)d_in[2];
    const float* ew  = (const float*)d_in[3];
    const float* Wr  = (const float*)d_in[4];
    const float* br  = (const float*)d_in[5];
    const float* W1  = (const float*)d_in[6];
    const float* b1  = (const float*)d_in[7];
    const float* W2  = (const float*)d_in[8];
    const float* b2  = (const float*)d_in[9];
    const float* W3  = (const float*)d_in[10];
    const float* b3  = (const float*)d_in[11];
    const float* Wop = (const float*)d_in[12];
    const float* bop = (const float*)d_in[13];
    float* out = (float*)d_out;

    const int n_nodes = in_sizes[0] / NF;   // 50000
    const int n_edges = in_sizes[1];        // 640000
    const size_t feat = (size_t)n_nodes * NF;

    float* res = (float*)d_ws;      // [n_nodes,128]
    float* agg = res + feat;        // [n_nodes,128]
    float* h   = agg + feat;        // [n_nodes,128]

    const int gemm_grid = (n_nodes + 63) / 64;
    const int scat_grid = (n_edges * 32 + 255) / 256;
    const int out_grid  = (n_nodes + 127) / 128;

    // res = x @ Wr + br
    gemm_nk128<0, 0><<<gemm_grid, 256, 0, stream>>>(x, Wr, br, nullptr, res, n_nodes);

    // layer 1
    hipMemsetAsync(agg, 0, feat * sizeof(float), stream);
    scatter_edges<<<scat_grid, 256, 0, stream>>>(x, src, dst, ew, agg, n_edges);
    gemm_nk128<1, 0><<<gemm_grid, 256, 0, stream>>>(agg, W1, b1, nullptr, h, n_nodes);

    // layer 2
    hipMemsetAsync(agg, 0, feat * sizeof(float), stream);
    scatter_edges<<<scat_grid, 256, 0, stream>>>(h, src, dst, ew, agg, n_edges);
    gemm_nk128<1, 0><<<gemm_grid, 256, 0, stream>>>(agg, W2, b2, nullptr, h, n_nodes);

    // layer 3 (+ residual, relu)
    hipMemsetAsync(agg, 0, feat * sizeof(float), stream);
    scatter_edges<<<scat_grid, 256, 0, stream>>>(h, src, dst, ew, agg, n_edges);
    gemm_nk128<1, 1><<<gemm_grid, 256, 0, stream>>>(agg, W3, b3, res, h, n_nodes);

    // output projection
    gemm_out40<<<out_grid, 256, 0, stream>>>(h, Wop, bop, out, n_nodes);
}

// Round 2
// 481.877 us; speedup vs baseline: 7.0666x; 7.0666x over previous
//
#include <hip/hip_runtime.h>
#include <stdint.h>

// ---------------------------------------------------------------------------
// GCN 3-layer + edge weights, fp32.
// v2: atomic-free aggregation via per-launch CSR (dst-bucketed) + node gather.
//   build: zero counts -> histogram(dst) -> single-block scan -> fill pairs
//   per layer: agg[n] = sum_{e in in(n)} x[src_e] * w_e   (gather, no atomics)
// ---------------------------------------------------------------------------

#define NF 128  // feature width for all hidden layers

// ============================ CSR build ====================================

__global__ __launch_bounds__(256) void hist_kernel(
    const int* __restrict__ dst, int* __restrict__ counts, int n_edges)
{
    int e = blockIdx.x * 256 + threadIdx.x;
    if (e < n_edges) atomicAdd(&counts[dst[e]], 1);
}

// single block, 1024 threads: in-place exclusive scan counts->rowptr, copy to cursor
__global__ __launch_bounds__(1024) void scan_kernel(
    int* __restrict__ counts /* in: counts, out: rowptr */,
    int* __restrict__ cursor, int n)
{
    __shared__ int partials[1024];
    const int t = threadIdx.x;
    const int chunk = (n + 1023) >> 10;
    const int begin = t * chunk;
    const int end = min(begin + chunk, n);
    int sum = 0;
    for (int i = begin; i < end; ++i) sum += counts[i];
    partials[t] = sum;
    __syncthreads();
    for (int off = 1; off < 1024; off <<= 1) {
        int v = (t >= off) ? partials[t - off] : 0;
        __syncthreads();
        partials[t] += v;
        __syncthreads();
    }
    int base = partials[t] - sum;  // exclusive prefix
    for (int i = begin; i < end; ++i) {
        int c = counts[i];
        counts[i] = base;
        cursor[i] = base;
        base += c;
    }
    if (t == 1023) counts[n] = partials[1023];
}

__global__ __launch_bounds__(256) void fill_kernel(
    const int* __restrict__ src, const int* __restrict__ dst,
    const float* __restrict__ ew, int* __restrict__ cursor,
    int2* __restrict__ pairs, int n_edges)
{
    int e = blockIdx.x * 256 + threadIdx.x;
    if (e >= n_edges) return;
    int pos = atomicAdd(&cursor[dst[e]], 1);
    pairs[pos] = make_int2(src[e], __float_as_int(ew[e]));
}

// ======================= gather aggregation ================================
// 32 lanes per node, float4 per lane = 128 features
__global__ __launch_bounds__(256) void agg_gather(
    const float* __restrict__ x, const int* __restrict__ rowptr,
    const int2* __restrict__ pairs, float* __restrict__ agg, int n_nodes)
{
    int gid = blockIdx.x * 256 + threadIdx.x;
    int node = gid >> 5;
    if (node >= n_nodes) return;
    int f = (gid & 31) << 2;
    int e0 = rowptr[node];
    int e1 = rowptr[node + 1];
    float4 acc = make_float4(0.f, 0.f, 0.f, 0.f);
    for (int e = e0; e < e1; ++e) {
        int2 p = pairs[e];
        float w = __int_as_float(p.y);
        const float4 v = *reinterpret_cast<const float4*>(x + (size_t)p.x * NF + f);
        acc.x = fmaf(v.x, w, acc.x);
        acc.y = fmaf(v.y, w, acc.y);
        acc.z = fmaf(v.z, w, acc.z);
        acc.w = fmaf(v.w, w, acc.w);
    }
    *reinterpret_cast<float4*>(agg + (size_t)node * NF + f) = acc;
}

// ================= fallback: atomic scatter (round-1 path) =================
__global__ __launch_bounds__(256) void scatter_edges(
    const float* __restrict__ x, const int* __restrict__ src,
    const int* __restrict__ dst, const float* __restrict__ ew,
    float* __restrict__ agg, int n_edges)
{
    int gid = blockIdx.x * 256 + threadIdx.x;
    int e = gid >> 5;
    if (e >= n_edges) return;
    int f = (gid & 31) << 2;
    int s = src[e];
    int d = dst[e];
    float w = ew[e];
    const float4 v = *reinterpret_cast<const float4*>(x + (size_t)s * NF + f);
    float* o = agg + (size_t)d * NF + f;
    atomicAdd(o + 0, v.x * w);
    atomicAdd(o + 1, v.y * w);
    atomicAdd(o + 2, v.z * w);
    atomicAdd(o + 3, v.w * w);
}

// ============================== GEMMs ======================================

// [nrows,128] @ [128,128] + bias (+res) (+relu), fp32
// block: 256 thr, tile 64 rows x 128 cols, thread tile 4x8, BK=32
template<int RELU, int RES>
__global__ __launch_bounds__(256) void gemm_nk128(
    const float* __restrict__ A, const float* __restrict__ W,
    const float* __restrict__ bias, const float* __restrict__ resid,
    float* __restrict__ out, int nrows)
{
    __shared__ float As[32][64];    // [k][r] transposed
    __shared__ float Bs[32][128];   // [k][c]
    const int tid = threadIdx.x;
    const int row0 = blockIdx.x * 64;
    const int tc = tid & 15;
    const int tr = tid >> 4;

    float acc[4][8];
    #pragma unroll
    for (int i = 0; i < 4; i++)
        #pragma unroll
        for (int j = 0; j < 8; j++) acc[i][j] = 0.f;

    for (int k0 = 0; k0 < 128; k0 += 32) {
        #pragma unroll
        for (int i = 0; i < 2; i++) {
            int t = tid + i * 256;
            int r = t & 63;
            int kk = (t >> 6) << 2;
            int gr = row0 + r;
            float4 v = make_float4(0.f, 0.f, 0.f, 0.f);
            if (gr < nrows)
                v = *reinterpret_cast<const float4*>(A + (size_t)gr * NF + k0 + kk);
            As[kk + 0][r] = v.x;
            As[kk + 1][r] = v.y;
            As[kk + 2][r] = v.z;
            As[kk + 3][r] = v.w;
        }
        #pragma unroll
        for (int i = 0; i < 4; i++) {
            int t = tid + i * 256;
            int kk = t >> 5;
            int c = (t & 31) << 2;
            *reinterpret_cast<float4*>(&Bs[kk][c]) =
                *reinterpret_cast<const float4*>(W + (size_t)(k0 + kk) * NF + c);
        }
        __syncthreads();
        #pragma unroll
        for (int k = 0; k < 32; k++) {
            float4 a  = *reinterpret_cast<float4*>(&As[k][tr << 2]);
            float4 b0 = *reinterpret_cast<float4*>(&Bs[k][tc << 3]);
            float4 b1 = *reinterpret_cast<float4*>(&Bs[k][(tc << 3) + 4]);
            float av[4] = {a.x, a.y, a.z, a.w};
            float bv[8] = {b0.x, b0.y, b0.z, b0.w, b1.x, b1.y, b1.z, b1.w};
            #pragma unroll
            for (int i = 0; i < 4; i++)
                #pragma unroll
                for (int j = 0; j < 8; j++)
                    acc[i][j] = fmaf(av[i], bv[j], acc[i][j]);
        }
        __syncthreads();
    }

    #pragma unroll
    for (int i = 0; i < 4; i++) {
        int gr = row0 + (tr << 2) + i;
        if (gr < nrows) {
            #pragma unroll
            for (int j = 0; j < 8; j++) {
                int c = (tc << 3) + j;
                float v = acc[i][j] + bias[c];
                if (RES) v += resid[(size_t)gr * NF + c];
                if (RELU) v = fmaxf(v, 0.f);
                out[(size_t)gr * NF + c] = v;
            }
        }
    }
}

// [nrows,128] @ [128,40] + bias
__global__ __launch_bounds__(256) void gemm_out40(
    const float* __restrict__ H, const float* __restrict__ Wop,
    const float* __restrict__ bop, float* __restrict__ out, int nrows)
{
    __shared__ float Hs[32][128];
    __shared__ float Ws[128 * 40];
    const int tid = threadIdx.x;
    const int row0 = blockIdx.x * 128;
    const int tc = tid & 3;
    const int tr = tid >> 2;

    #pragma unroll
    for (int i = 0; i < 20; i++) Ws[tid + i * 256] = Wop[tid + i * 256];

    float acc[2][10];
    #pragma unroll
    for (int i = 0; i < 2; i++)
        #pragma unroll
        for (int j = 0; j < 10; j++) acc[i][j] = 0.f;

    for (int k0 = 0; k0 < 128; k0 += 32) {
        #pragma unroll
        for (int i = 0; i < 4; i++) {
            int t = tid + i * 256;
            int r = t & 127;
            int kk = (t >> 7) << 2;
            int gr = row0 + r;
            float4 v = make_float4(0.f, 0.f, 0.f, 0.f);
            if (gr < nrows)
                v = *reinterpret_cast<const float4*>(H + (size_t)gr * NF + k0 + kk);
            Hs[kk + 0][r] = v.x;
            Hs[kk + 1][r] = v.y;
            Hs[kk + 2][r] = v.z;
            Hs[kk + 3][r] = v.w;
        }
        __syncthreads();
        #pragma unroll
        for (int k = 0; k < 32; k++) {
            float2 a = *reinterpret_cast<float2*>(&Hs[k][tr * 2]);
            #pragma unroll
            for (int j = 0; j < 10; j++) {
                float b = Ws[(k0 + k) * 40 + tc * 10 + j];
                acc[0][j] = fmaf(a.x, b, acc[0][j]);
                acc[1][j] = fmaf(a.y, b, acc[1][j]);
            }
        }
        __syncthreads();
    }

    #pragma unroll
    for (int i = 0; i < 2; i++) {
        int gr = row0 + tr * 2 + i;
        if (gr < nrows) {
            #pragma unroll
            for (int j = 0; j < 10; j++) {
                int c = tc * 10 + j;
                out[(size_t)gr * 40 + c] = acc[i][j] + bop[c];
            }
        }
    }
}

// ============================== launch =====================================

extern "C" void kernel_launch(void* const* d_in, const int* in_sizes, int n_in,
                              void* d_out, int out_size, void* d_ws, size_t ws_size,
                              hipStream_t stream)
{
    const float* x   = (const float*)d_in[0];
    const int*   src = (const int*)d_in[1];
    const int*   dst = (const int*)d_in[2];
    const float* ew  = (const float*)d_in[3];
    const float* Wr  = (const float*)d_in[4];
    const float* br  = (const float*)d_in[5];
    const float* W1  = (const float*)d_in[6];
    const float* b1  = (const float*)d_in[7];
    const float* W2  = (const float*)d_in[8];
    const float* b2  = (const float*)d_in[9];
    const float* W3  = (const float*)d_in[10];
    const float* b3  = (const float*)d_in[11];
    const float* Wop = (const float*)d_in[12];
    const float* bop = (const float*)d_in[13];
    float* out = (float*)d_out;

    const int n_nodes = in_sizes[0] / NF;   // 50000
    const int n_edges = in_sizes[1];        // 640000
    const size_t feat = (size_t)n_nodes * NF;

    float* res = (float*)d_ws;      // [n_nodes,128]
    float* agg = res + feat;        // [n_nodes,128]
    float* h   = agg + feat;        // [n_nodes,128]
    int* rowptr = (int*)(h + feat);             // n_nodes+1 (counts -> rowptr)
    int* cursor = rowptr + (n_nodes + 1);       // n_nodes
    int2* pairs = (int2*)(((uintptr_t)(cursor + n_nodes) + 15) & ~(uintptr_t)15);
    const size_t needed = (size_t)((char*)(pairs + n_edges) - (char*)d_ws);
    const bool use_csr = (needed <= ws_size);

    const int gemm_grid = (n_nodes + 63) / 64;
    const int out_grid  = (n_nodes + 127) / 128;
    const int edge_grid = (n_edges + 255) / 256;
    const int agg_grid  = (n_nodes * 32 + 255) / 256;
    const int scat_grid = (n_edges * 32 + 255) / 256;

    if (use_csr) {
        // ---- build CSR (dst-bucketed), reused by all 3 layers ----
        hipMemsetAsync(rowptr, 0, (size_t)(n_nodes + 1) * sizeof(int), stream);
        hist_kernel<<<edge_grid, 256, 0, stream>>>(dst, rowptr, n_edges);
        scan_kernel<<<1, 1024, 0, stream>>>(rowptr, cursor, n_nodes);
        fill_kernel<<<edge_grid, 256, 0, stream>>>(src, dst, ew, cursor, pairs, n_edges);
    }

    // res = x @ Wr + br
    gemm_nk128<0, 0><<<gemm_grid, 256, 0, stream>>>(x, Wr, br, nullptr, res, n_nodes);

    for (int layer = 0; layer < 3; ++layer) {
        const float* in_feat = (layer == 0) ? x : h;
        if (use_csr) {
            agg_gather<<<agg_grid, 256, 0, stream>>>(in_feat, rowptr, pairs, agg, n_nodes);
        } else {
            hipMemsetAsync(agg, 0, feat * sizeof(float), stream);
            scatter_edges<<<scat_grid, 256, 0, stream>>>(in_feat, src, dst, ew, agg, n_edges);
        }
        if (layer == 0)
            gemm_nk128<1, 0><<<gemm_grid, 256, 0, stream>>>(agg, W1, b1, nullptr, h, n_nodes);
        else if (layer == 1)
            gemm_nk128<1, 0><<<gemm_grid, 256, 0, stream>>>(agg, W2, b2, nullptr, h, n_nodes);
        else
            gemm_nk128<1, 1><<<gemm_grid, 256, 0, stream>>>(agg, W3, b3, res, h, n_nodes);
    }

    // output projection
    gemm_out40<<<out_grid, 256, 0, stream>>>(h, Wop, bop, out, n_nodes);
}

// Round 3
// 247.064 us; speedup vs baseline: 13.7828x; 1.9504x over previous
//
#include <hip/hip_runtime.h>
#include <stdint.h>

// ---------------------------------------------------------------------------
// GCN 3-layer + edge weights.
// v3: CSR gather (atomic-free) + hierarchical scan + bf16 features +
//     bf16 MFMA GEMMs (16x16x32), fp32 accumulate.
// ---------------------------------------------------------------------------

#define NF 128

typedef unsigned short u16;
typedef __attribute__((ext_vector_type(8))) short short8;   // 8 bf16 = 16 B
typedef __attribute__((ext_vector_type(4))) float f32x4;

__device__ __forceinline__ float bf2f(u16 v) {
    union { unsigned u; float f; } x; x.u = (unsigned)v << 16; return x.f;
}
__device__ __forceinline__ u16 f2bf(float f) {
    union { float f; unsigned u; } x; x.f = f;
    unsigned r = (x.u + 0x7FFFu + ((x.u >> 16) & 1u)) >> 16;
    return (u16)r;
}

// ============================ CSR build ====================================

__global__ __launch_bounds__(256) void hist_kernel(
    const int* __restrict__ dst, int* __restrict__ counts, int n_edges)
{
    int e = blockIdx.x * 256 + threadIdx.x;
    if (e < n_edges) atomicAdd(&counts[dst[e]], 1);
}

// pass1: per-block (256-wide) sums of counts
__global__ __launch_bounds__(256) void scan_pass1(
    const int* __restrict__ counts, int* __restrict__ bsums, int n)
{
    __shared__ int s[256];
    int i = blockIdx.x * 256 + threadIdx.x;
    s[threadIdx.x] = (i < n) ? counts[i] : 0;
    __syncthreads();
    for (int off = 128; off > 0; off >>= 1) {
        if (threadIdx.x < off) s[threadIdx.x] += s[threadIdx.x + off];
        __syncthreads();
    }
    if (threadIdx.x == 0) bsums[blockIdx.x] = s[0];
}

// pass2: single block exclusive-scans bsums[0..G-1] (G<=256), total -> bsums[G]
__global__ __launch_bounds__(256) void scan_pass2(int* __restrict__ bsums, int G)
{
    __shared__ int s[256];
    int t = threadIdx.x;
    int v = (t < G) ? bsums[t] : 0;
    s[t] = v;
    __syncthreads();
    for (int off = 1; off < 256; off <<= 1) {
        int u = (t >= off) ? s[t - off] : 0;
        __syncthreads();
        s[t] += u;
        __syncthreads();
    }
    if (t < G) bsums[t] = s[t] - v;          // exclusive
    if (t == 0) bsums[G] = s[255];           // total
}

// pass3: per-block exclusive scan + block offset; in-place counts->rowptr, copy cursor
__global__ __launch_bounds__(256) void scan_pass3(
    int* __restrict__ rowptr /* counts in, rowptr out */,
    const int* __restrict__ bsums, int* __restrict__ cursor, int n, int G)
{
    __shared__ int s[256];
    int t = threadIdx.x;
    int i = blockIdx.x * 256 + t;
    int v = (i < n) ? rowptr[i] : 0;
    s[t] = v;
    __syncthreads();
    for (int off = 1; off < 256; off <<= 1) {
        int u = (t >= off) ? s[t - off] : 0;
        __syncthreads();
        s[t] += u;
        __syncthreads();
    }
    int excl = s[t] - v + bsums[blockIdx.x];
    if (i < n) { rowptr[i] = excl; cursor[i] = excl; }
    if (i == 0) rowptr[n] = bsums[G];
}

__global__ __launch_bounds__(256) void fill_kernel(
    const int* __restrict__ src, const int* __restrict__ dst,
    const float* __restrict__ ew, int* __restrict__ cursor,
    int2* __restrict__ pairs, int n_edges)
{
    int e = blockIdx.x * 256 + threadIdx.x;
    if (e >= n_edges) return;
    int pos = atomicAdd(&cursor[dst[e]], 1);
    pairs[pos] = make_int2(src[e], __float_as_int(ew[e]));
}

// ============================ casts ========================================

__global__ __launch_bounds__(256) void cast_x_bf16(
    const float* __restrict__ in, u16* __restrict__ out, int n_elem)
{
    int idx = (blockIdx.x * 256 + threadIdx.x) * 4;
    if (idx >= n_elem) return;
    float4 v = *reinterpret_cast<const float4*>(in + idx);
    ushort4 o;
    o.x = f2bf(v.x); o.y = f2bf(v.y); o.z = f2bf(v.z); o.w = f2bf(v.w);
    *reinterpret_cast<ushort4*>(out + idx) = o;
}

// transpose + cast all weights: Wt[w][n][k] = W[k][n] bf16; Wtop[48][128] zero-pad
__global__ __launch_bounds__(256) void prep_weights(
    const float* __restrict__ Wr, const float* __restrict__ W1,
    const float* __restrict__ W2, const float* __restrict__ W3,
    const float* __restrict__ Wop, u16* __restrict__ Wt, u16* __restrict__ Wtop)
{
    int i = blockIdx.x * 256 + threadIdx.x;
    if (i < 4 * 16384) {
        int w = i >> 14, r = i & 16383;
        int nn = r >> 7, kk = r & 127;
        const float* W = (w == 0) ? Wr : (w == 1) ? W1 : (w == 2) ? W2 : W3;
        Wt[i] = f2bf(W[kk * NF + nn]);
    } else {
        int r = i - 4 * 16384;
        if (r < 48 * 128) {
            int nn = r >> 7, kk = r & 127;
            Wtop[r] = (nn < 40) ? f2bf(Wop[kk * 40 + nn]) : (u16)0;
        }
    }
}

// ======================= gather aggregation (bf16) =========================
// 16 lanes per node, 8 features (16 B) per lane
__global__ __launch_bounds__(256) void agg_gather_b(
    const u16* __restrict__ xb, const int* __restrict__ rowptr,
    const int2* __restrict__ pairs, u16* __restrict__ aggb, int n_nodes)
{
    int gid = blockIdx.x * 256 + threadIdx.x;
    int node = gid >> 4;
    if (node >= n_nodes) return;
    int f = (gid & 15) << 3;
    int e0 = rowptr[node];
    int e1 = rowptr[node + 1];
    float acc[8];
    #pragma unroll
    for (int j = 0; j < 8; j++) acc[j] = 0.f;
    for (int e = e0; e < e1; ++e) {
        int2 p = pairs[e];
        float w = __int_as_float(p.y);
        short8 v = *reinterpret_cast<const short8*>(xb + (size_t)p.x * NF + f);
        #pragma unroll
        for (int j = 0; j < 8; j++)
            acc[j] = fmaf(bf2f((u16)v[j]), w, acc[j]);
    }
    short8 o;
    #pragma unroll
    for (int j = 0; j < 8; j++) o[j] = (short)f2bf(acc[j]);
    *reinterpret_cast<short8*>(aggb + (size_t)node * NF + f) = o;
}

// ========================= MFMA GEMMs (bf16) ===============================
// A[nrows][128] bf16, Wt[n=128][k=128] bf16 (pre-transposed), bias fp32,
// out[nrows][128] bf16. Block: 256 thr = 4 waves, 64 rows; wave = 16 rows.
// mfma_f32_16x16x32_bf16: A lane row=lane&15, k=(lane>>4)*8+e;
//                         B lane col=lane&15, k=(lane>>4)*8+e;
//                         D lane col=lane&15, row=(lane>>4)*4+reg.
template<int RELU, int RES>
__global__ __launch_bounds__(256) void gemm_mfma128(
    const u16* __restrict__ A, const u16* __restrict__ Wt,
    const float* __restrict__ bias, const u16* __restrict__ resid,
    u16* __restrict__ out, int nrows)
{
    __shared__ u16 Bs[128 * 128];   // 32 KB, granule-XOR swizzled
    const int tid = threadIdx.x;

    // stage Wt swizzled: 2048 granules of 16 B; granule g of row -> g^(row&7)
    #pragma unroll
    for (int i = 0; i < 8; i++) {
        int G = tid + i * 256;
        int row = G >> 4, g = G & 15;
        int gs = g ^ (row & 7);
        *reinterpret_cast<short8*>(&Bs[row * NF + gs * 8]) =
            *reinterpret_cast<const short8*>(Wt + (size_t)G * 8);
    }

    const int wave = tid >> 6, lane = tid & 63;
    const int lrow = lane & 15, lk = lane >> 4;
    const int row0 = blockIdx.x * 64 + wave * 16;
    const int grow = row0 + lrow;

    short8 a[4];
    if (grow < nrows) {
        const u16* Ar = A + (size_t)grow * NF + lk * 8;
        #pragma unroll
        for (int t = 0; t < 4; t++)
            a[t] = *reinterpret_cast<const short8*>(Ar + t * 32);
    } else {
        #pragma unroll
        for (int t = 0; t < 4; t++)
            #pragma unroll
            for (int j = 0; j < 8; j++) a[t][j] = 0;
    }
    __syncthreads();

    f32x4 acc[8];
    #pragma unroll
    for (int c = 0; c < 8; c++) { acc[c][0]=0.f; acc[c][1]=0.f; acc[c][2]=0.f; acc[c][3]=0.f; }

    #pragma unroll
    for (int t = 0; t < 4; t++) {
        #pragma unroll
        for (int c = 0; c < 8; c++) {
            int col = c * 16 + lrow;
            int g = t * 4 + lk;
            int gs = g ^ (col & 7);
            short8 b = *reinterpret_cast<const short8*>(&Bs[col * NF + gs * 8]);
            acc[c] = __builtin_amdgcn_mfma_f32_16x16x32_bf16(a[t], b, acc[c], 0, 0, 0);
        }
    }

    #pragma unroll
    for (int c = 0; c < 8; c++) {
        int col = c * 16 + lrow;
        float bv = bias[col];
        #pragma unroll
        for (int r = 0; r < 4; r++) {
            int orow = row0 + lk * 4 + r;
            if (orow < nrows) {
                float v = acc[c][r] + bv;
                if (RES) v += bf2f(resid[(size_t)orow * NF + col]);
                if (RELU) v = fmaxf(v, 0.f);
                out[(size_t)orow * NF + col] = f2bf(v);
            }
        }
    }
}

// H[nrows][128] bf16 @ Wtop[48][128] bf16 -> out[nrows][40] fp32 (+bias)
__global__ __launch_bounds__(256) void gemm_out40_mfma(
    const u16* __restrict__ H, const u16* __restrict__ Wtop,
    const float* __restrict__ bop, float* __restrict__ out, int nrows)
{
    __shared__ u16 Bs[48 * 128];    // 12 KB swizzled
    const int tid = threadIdx.x;
    #pragma unroll
    for (int i = 0; i < 3; i++) {
        int G = tid + i * 256;      // 768 granules
        int row = G >> 4, g = G & 15;
        int gs = g ^ (row & 7);
        *reinterpret_cast<short8*>(&Bs[row * NF + gs * 8]) =
            *reinterpret_cast<const short8*>(Wtop + (size_t)G * 8);
    }

    const int wave = tid >> 6, lane = tid & 63;
    const int lrow = lane & 15, lk = lane >> 4;
    const int row0 = blockIdx.x * 64 + wave * 16;
    const int grow = row0 + lrow;

    short8 a[4];
    if (grow < nrows) {
        const u16* Hr = H + (size_t)grow * NF + lk * 8;
        #pragma unroll
        for (int t = 0; t < 4; t++)
            a[t] = *reinterpret_cast<const short8*>(Hr + t * 32);
    } else {
        #pragma unroll
        for (int t = 0; t < 4; t++)
            #pragma unroll
            for (int j = 0; j < 8; j++) a[t][j] = 0;
    }
    __syncthreads();

    f32x4 acc[3];
    #pragma unroll
    for (int c = 0; c < 3; c++) { acc[c][0]=0.f; acc[c][1]=0.f; acc[c][2]=0.f; acc[c][3]=0.f; }

    #pragma unroll
    for (int t = 0; t < 4; t++) {
        #pragma unroll
        for (int c = 0; c < 3; c++) {
            int col = c * 16 + lrow;
            int g = t * 4 + lk;
            int gs = g ^ (col & 7);
            short8 b = *reinterpret_cast<const short8*>(&Bs[col * NF + gs * 8]);
            acc[c] = __builtin_amdgcn_mfma_f32_16x16x32_bf16(a[t], b, acc[c], 0, 0, 0);
        }
    }

    #pragma unroll
    for (int c = 0; c < 3; c++) {
        int col = c * 16 + lrow;
        if (col < 40) {
            float bv = bop[col];
            #pragma unroll
            for (int r = 0; r < 4; r++) {
                int orow = row0 + lk * 4 + r;
                if (orow < nrows)
                    out[(size_t)orow * 40 + col] = acc[c][r] + bv;
            }
        }
    }
}

// ============================== launch =====================================

extern "C" void kernel_launch(void* const* d_in, const int* in_sizes, int n_in,
                              void* d_out, int out_size, void* d_ws, size_t ws_size,
                              hipStream_t stream)
{
    const float* x   = (const float*)d_in[0];
    const int*   src = (const int*)d_in[1];
    const int*   dst = (const int*)d_in[2];
    const float* ew  = (const float*)d_in[3];
    const float* Wr  = (const float*)d_in[4];
    const float* br  = (const float*)d_in[5];
    const float* W1  = (const float*)d_in[6];
    const float* b1  = (const float*)d_in[7];
    const float* W2  = (const float*)d_in[8];
    const float* b2  = (const float*)d_in[9];
    const float* W3  = (const float*)d_in[10];
    const float* b3  = (const float*)d_in[11];
    const float* Wop = (const float*)d_in[12];
    const float* bop = (const float*)d_in[13];
    float* out = (float*)d_out;

    const int n_nodes = in_sizes[0] / NF;   // 50000
    const int n_edges = in_sizes[1];        // 640000
    const size_t feat = (size_t)n_nodes * NF;

    // workspace layout (bf16 feature buffers)
    u16* xb   = (u16*)d_ws;
    u16* hb   = xb + feat;
    u16* aggb = hb + feat;
    u16* resb = aggb + feat;
    u16* Wt   = resb + feat;                 // 4 * 128*128
    u16* Wtop = Wt + 4 * 16384;              // 48*128
    int* rowptr = (int*)(Wtop + 48 * 128);   // n+1 (counts -> rowptr)
    int* cursor = rowptr + (n_nodes + 1);
    const int G1 = (n_nodes + 255) / 256;
    int* bsums  = cursor + n_nodes;          // G1+1
    int2* pairs = (int2*)(((uintptr_t)(bsums + G1 + 1) + 15) & ~(uintptr_t)15);

    const int edge_grid = (n_edges + 255) / 256;
    const int gemm_grid = (n_nodes + 63) / 64;
    const int agg_grid  = (n_nodes * 16 + 255) / 256;
    const int castx_grid = ((int)feat / 4 + 255) / 256;

    // ---- CSR build ----
    hipMemsetAsync(rowptr, 0, (size_t)(n_nodes + 1) * sizeof(int), stream);
    hist_kernel<<<edge_grid, 256, 0, stream>>>(dst, rowptr, n_edges);
    scan_pass1<<<G1, 256, 0, stream>>>(rowptr, bsums, n_nodes);
    scan_pass2<<<1, 256, 0, stream>>>(bsums, G1);
    scan_pass3<<<G1, 256, 0, stream>>>(rowptr, bsums, cursor, n_nodes, G1);
    fill_kernel<<<edge_grid, 256, 0, stream>>>(src, dst, ew, cursor, pairs, n_edges);

    // ---- casts ----
    cast_x_bf16<<<castx_grid, 256, 0, stream>>>(x, xb, (int)feat);
    prep_weights<<<(4 * 16384 + 48 * 128 + 255) / 256, 256, 0, stream>>>(
        Wr, W1, W2, W3, Wop, Wt, Wtop);

    // ---- res = x @ Wr + br (bf16 out) ----
    gemm_mfma128<0, 0><<<gemm_grid, 256, 0, stream>>>(xb, Wt, br, nullptr, resb, n_nodes);

    // ---- 3 GCN layers ----
    agg_gather_b<<<agg_grid, 256, 0, stream>>>(xb, rowptr, pairs, aggb, n_nodes);
    gemm_mfma128<1, 0><<<gemm_grid, 256, 0, stream>>>(aggb, Wt + 16384, b1, nullptr, hb, n_nodes);

    agg_gather_b<<<agg_grid, 256, 0, stream>>>(hb, rowptr, pairs, aggb, n_nodes);
    gemm_mfma128<1, 0><<<gemm_grid, 256, 0, stream>>>(aggb, Wt + 2 * 16384, b2, nullptr, hb, n_nodes);

    agg_gather_b<<<agg_grid, 256, 0, stream>>>(hb, rowptr, pairs, aggb, n_nodes);
    gemm_mfma128<1, 1><<<gemm_grid, 256, 0, stream>>>(aggb, Wt + 3 * 16384, b3, resb, hb, n_nodes);

    // ---- output projection ----
    gemm_out40_mfma<<<gemm_grid, 256, 0, stream>>>(hb, Wtop, bop, out, n_nodes);
}